// Round 1
// baseline (447.071 us; speedup 1.0000x reference)
//
#include <hip/hip_runtime.h>
#include <hip/hip_bf16.h>

// OTNoiseGate: B=8192, E=8, D=512, P=32, eps=0.05, 50 Sinkhorn iters.
// ns=2 Sinkhorn collapses to a scalar recurrence on delta = lu0-lu1 (base-2):
//   T = sum_p 1/(1+2^(d_p+delta));  delta += log2(T) - log2(32-T)
// final transport rows: t0 = (1-sigma)/32, t1 = sigma/32.

#if defined(__has_builtin)
# if __has_builtin(__builtin_amdgcn_exp2f)
#  define EXP2F(x) __builtin_amdgcn_exp2f(x)
# else
#  define EXP2F(x) exp2f(x)
# endif
# if __has_builtin(__builtin_amdgcn_logf)
#  define LOG2F(x) __builtin_amdgcn_logf(x)
# else
#  define LOG2F(x) log2f(x)
# endif
# if __has_builtin(__builtin_amdgcn_rcpf)
#  define RCPF(x) __builtin_amdgcn_rcpf(x)
# else
#  define RCPF(x) (1.0f/(x))
# endif
#else
# define EXP2F(x) exp2f(x)
# define LOG2F(x) log2f(x)
# define RCPF(x) (1.0f/(x))
#endif

#define BDIM   8192
#define EDIM   8
#define DDIM   512
#define PDIM   32
#define BPB    16          // b's per block (2 problems per wave * 8 waves)
#define NTHR   512
#define C_SCALE 28.853900817779268f   // log2(e)/eps = 1.442695/0.05
#define LOG2E   1.4426950408889634f

__device__ __forceinline__ float bsum32(float x) {
  x += __shfl_xor(x, 1);
  x += __shfl_xor(x, 2);
  x += __shfl_xor(x, 4);
  x += __shfl_xor(x, 8);
  x += __shfl_xor(x, 16);
  return x;
}
__device__ __forceinline__ float bmax32(float x) {
  x = fmaxf(x, __shfl_xor(x, 1));
  x = fmaxf(x, __shfl_xor(x, 2));
  x = fmaxf(x, __shfl_xor(x, 4));
  x = fmaxf(x, __shfl_xor(x, 8));
  x = fmaxf(x, __shfl_xor(x, 16));
  return x;
}

__global__ __launch_bounds__(NTHR, 4)   // 8 waves/block, 2 blocks/CU (LDS 64KiB)
void ot_noise_gate_kernel(const float* __restrict__ tokens,
                          const float* __restrict__ protos,
                          const int*   __restrict__ fullIndexPtr,
                          float*       __restrict__ out) {
  const int fi = fullIndexPtr[0];
  const int e  = blockIdx.x & (EDIM - 1);
  const int b0 = (blockIdx.x >> 3) * BPB;
  float* outVal = out;                       // validity (B,E,1) flat
  float* outOt  = out + BDIM * EDIM;         // ot_cost  (B,E)

  if (e == fi) {                             // masked slice: constants
    int t = threadIdx.x;
    if (t < BPB) {
      int b = b0 + t;
      outVal[b * EDIM + e] = 1.0f;
      outOt [b * EDIM + e] = 0.0f;
    }
    return;
  }

  // ---- stage prototypes[e] into LDS, xor-swizzled float4 blocks -------------
  __shared__ float sP[PDIM * DDIM];          // 64 KiB
  float4* sP4 = (float4*)sP;
  const float4* pG4 = (const float4*)(protos + (size_t)e * PDIM * DDIM);
  for (int idx = threadIdx.x; idx < PDIM * DDIM / 4; idx += NTHR) {
    int p = idx >> 7, j = idx & 127;
    sP4[p * 128 + (j ^ p)] = pG4[p * 128 + j];
  }

  const int lane = threadIdx.x & 63;
  const int wave = threadIdx.x >> 6;
  const int prob = (wave << 1) | (lane >> 5);   // 0..15 within block
  const int p    = lane & 31;
  const int b    = b0 + prob;
  const float4* tok4 = (const float4*)(tokens + ((size_t)b * EDIM + e)  * DDIM);
  const float4* anc4 = (const float4*)(tokens + ((size_t)b * EDIM + fi) * DDIM);

  // ---- row norms (coalesced: lane p takes chunk 32k+p) ----------------------
  float tt = 0.f, aa = 0.f;
  #pragma unroll
  for (int k = 0; k < 4; ++k) {
    float4 t = tok4[32 * k + p];
    float4 a = anc4[32 * k + p];
    tt += t.x*t.x + t.y*t.y + t.z*t.z + t.w*t.w;
    aa += a.x*a.x + a.y*a.y + a.z*a.z + a.w*a.w;
  }
  tt = bsum32(tt);
  aa = bsum32(aa);

  __syncthreads();

  // ---- cross terms + proto norm: lane p vs prototype p ----------------------
  float cr0 = 0.f, cr1 = 0.f, pp = 0.f;
  #pragma unroll 8
  for (int j = 0; j < 128; ++j) {
    float4 pr = sP4[p * 128 + (j ^ p)];
    float4 t  = tok4[j];
    float4 a  = anc4[j];
    cr0 += t.x*pr.x + t.y*pr.y + t.z*pr.z + t.w*pr.w;
    cr1 += a.x*pr.x + a.y*pr.y + a.z*pr.z + a.w*pr.w;
    pp  += pr.x*pr.x + pr.y*pr.y + pr.z*pr.z + pr.w*pr.w;
  }
  float c0 = fmaxf(tt - 2.f * cr0 + pp, 0.f);   // cost row 0 (tokens)
  float c1 = fmaxf(aa - 2.f * cr1 + pp, 0.f);   // cost row 1 (anchor)

  // ---- Sinkhorn: scalar recurrence on delta = lu0 - lu1 (base-2 domain) -----
  float ka = -c0 * C_SCALE;
  float kb = -c1 * C_SCALE;
  float dp = ka - kb;

  // iteration 1 exactly as reference (lv = 0): delta1 = log2(S1) - log2(S0)
  float ma = bmax32(ka), mb = bmax32(kb);
  float sa = bsum32(EXP2F(ka - ma));
  float sb = bsum32(EXP2F(kb - mb));
  float delta = (mb + LOG2F(sb)) - (ma + LOG2F(sa));

  // iterations 2..50
  for (int it = 0; it < 49; ++it) {
    float w  = EXP2F(dp + delta);
    float sg = RCPF(1.0f + w);        // sigma_p; overflow-safe (inf -> 0)
    float T  = bsum32(sg);            // in (0,32)
    delta += LOG2F(T) - LOG2F(32.0f - T);
  }

  // ---- final transport & outputs -------------------------------------------
  float sg = RCPF(1.0f + EXP2F(dp + delta));
  float ot = bsum32(c0 + sg * (c1 - c0)) * 0.03125f;
  if (p == 0) {
    float val = RCPF(1.0f + EXP2F(LOG2E * 6.0f * (ot - 0.25f)));
    outVal[b * EDIM + e] = val;
    outOt [b * EDIM + e] = ot;
  }
}

extern "C" void kernel_launch(void* const* d_in, const int* in_sizes, int n_in,
                              void* d_out, int out_size, void* d_ws, size_t ws_size,
                              hipStream_t stream) {
  const float* tokens = (const float*)d_in[0];   // (8192, 8, 512) fp32
  const float* protos = (const float*)d_in[1];   // (8, 32, 512) fp32
  const int*   fidx   = (const int*)d_in[2];     // scalar
  float* out = (float*)d_out;                    // 65536 validity + 65536 ot

  dim3 grid((BDIM / BPB) * EDIM);                // 4096 blocks
  dim3 block(NTHR);
  ot_noise_gate_kernel<<<grid, block, 0, stream>>>(tokens, protos, fidx, out);
}

// Round 2
// 444.251 us; speedup vs baseline: 1.0063x; 1.0063x over previous
//
#include <hip/hip_runtime.h>
#include <hip/hip_bf16.h>

// OTNoiseGate: B=8192, E=8, D=512, P=32, eps=0.05, 50 Sinkhorn iters.
// ns=2 Sinkhorn collapses to a scalar recurrence on delta = lu0-lu1 (base-2):
//   sigma_p = 1/(1+2^(d_p+delta));  T = sum_p sigma_p;  delta += log2(T)-log2(32-T)
// final transport rows: t0 = (1-sigma)/32, t1 = sigma/32.
// R2: Sinkhorn transposed to lane-owns-problem layout (no LDS-pipe cross-lane
// in the loop; only DPP quad shuffles), p2 hoisted to a pre-kernel, protos
// staged in two D-halves (LDS 37KB -> 4 blocks/CU).

#define EXP2F(x) __builtin_amdgcn_exp2f(x)
#define LOG2F(x) __builtin_amdgcn_logf(x)   // v_log_f32 = log2
#define RCPF(x)  __builtin_amdgcn_rcpf(x)

#define BDIM   8192
#define EDIM   8
#define DDIM   512
#define PDIM   32
#define BPB    16          // problems (b's) per block
#define NTHR   512
#define C_SCALE 28.853900817779268f   // log2(e)/eps
#define LOG2E   1.4426950408889634f

__device__ __forceinline__ float bsum32(float x) {
  x += __shfl_xor(x, 1);
  x += __shfl_xor(x, 2);
  x += __shfl_xor(x, 4);
  x += __shfl_xor(x, 8);
  x += __shfl_xor(x, 16);
  return x;
}
__device__ __forceinline__ float qsum4(float x) {   // sum within quad (DPP)
  x += __shfl_xor(x, 1);
  x += __shfl_xor(x, 2);
  return x;
}
__device__ __forceinline__ float qmax4(float x) {
  x = fmaxf(x, __shfl_xor(x, 1));
  x = fmaxf(x, __shfl_xor(x, 2));
  return x;
}

// ---- pre-kernel: p2[e][p] = ||proto_e_p||^2  (8*32 = 256 values) ------------
__global__ void proto_norms_kernel(const float* __restrict__ protos,
                                   float* __restrict__ pn) {
  int t = threadIdx.x;                      // 256 threads == rows (e*32+p)
  const float4* row = (const float4*)(protos + (size_t)t * DDIM);
  float s = 0.f;
  #pragma unroll 8
  for (int j = 0; j < DDIM / 4; ++j) {
    float4 v = row[j];
    s += v.x * v.x + v.y * v.y + v.z * v.z + v.w * v.w;
  }
  pn[t] = s;
}

__global__ __launch_bounds__(NTHR, 8)   // cap VGPR<=64 -> 4 blocks/CU w/ 37KB LDS
void ot_noise_gate_kernel(const float* __restrict__ tokens,
                          const float* __restrict__ protos,
                          const float* __restrict__ protoNorm,
                          const int*   __restrict__ fullIndexPtr,
                          float*       __restrict__ out) {
  const int fi = fullIndexPtr[0];
  const int e  = blockIdx.x & (EDIM - 1);
  const int b0 = (blockIdx.x >> 3) * BPB;
  float* outVal = out;                       // validity (B,E,1) flat
  float* outOt  = out + BDIM * EDIM;         // ot_cost  (B,E)

  if (e == fi) {                             // masked slice: constants
    int t = threadIdx.x;
    if (t < BPB) {
      int b = b0 + t;
      outVal[b * EDIM + e] = 1.0f;
      outOt [b * EDIM + e] = 0.0f;
    }
    return;
  }

  __shared__ float sP[PDIM * (DDIM / 2)];    // 32 KiB: half-D proto stage
  __shared__ float sC0[BPB][PDIM + 1];       // cost row 0, padded
  __shared__ float sC1[BPB][PDIM + 1];       // cost row 1
  float4* sP4 = (float4*)sP;
  const float4* pG4 = (const float4*)(protos + (size_t)e * PDIM * DDIM);

  const int lane = threadIdx.x & 63;
  const int wave = threadIdx.x >> 6;
  const int prob = (wave << 1) | (lane >> 5);   // 0..15 within block
  const int p    = lane & 31;
  const int b    = b0 + prob;
  const float4* tok4 = (const float4*)(tokens + ((size_t)b * EDIM + e)  * DDIM);
  const float4* anc4 = (const float4*)(tokens + ((size_t)b * EDIM + fi) * DDIM);

  const float pp = protoNorm[e * PDIM + p];     // ||proto||^2 (pre-kernel)

  // ---- stage half 0 ---------------------------------------------------------
  for (int idx = threadIdx.x; idx < PDIM * 64; idx += NTHR) {
    int pr = idx >> 6, j = idx & 63;
    sP4[pr * 64 + (j ^ pr)] = pG4[pr * 128 + j];
  }

  // ---- row norms (overlap with staging latency) -----------------------------
  float tt = 0.f, aa = 0.f;
  #pragma unroll
  for (int k = 0; k < 4; ++k) {
    float4 t = tok4[32 * k + p];
    float4 a = anc4[32 * k + p];
    tt += t.x * t.x + t.y * t.y + t.z * t.z + t.w * t.w;
    aa += a.x * a.x + a.y * a.y + a.z * a.z + a.w * a.w;
  }
  tt = bsum32(tt);
  aa = bsum32(aa);

  __syncthreads();

  // ---- cross terms, half 0 --------------------------------------------------
  float cr0 = 0.f, cr1 = 0.f;
  #pragma unroll 4
  for (int j = 0; j < 64; ++j) {
    float4 pr = sP4[p * 64 + (j ^ p)];
    float4 t  = tok4[j];
    float4 a  = anc4[j];
    cr0 += t.x * pr.x + t.y * pr.y + t.z * pr.z + t.w * pr.w;
    cr1 += a.x * pr.x + a.y * pr.y + a.z * pr.z + a.w * pr.w;
  }
  __syncthreads();

  // ---- stage half 1 ---------------------------------------------------------
  for (int idx = threadIdx.x; idx < PDIM * 64; idx += NTHR) {
    int pr = idx >> 6, j = idx & 63;
    sP4[pr * 64 + (j ^ pr)] = pG4[pr * 128 + 64 + j];
  }
  __syncthreads();

  // ---- cross terms, half 1 --------------------------------------------------
  #pragma unroll 4
  for (int j = 0; j < 64; ++j) {
    float4 pr = sP4[p * 64 + (j ^ p)];
    float4 t  = tok4[64 + j];
    float4 a  = anc4[64 + j];
    cr0 += t.x * pr.x + t.y * pr.y + t.z * pr.z + t.w * pr.w;
    cr1 += a.x * pr.x + a.y * pr.y + a.z * pr.z + a.w * pr.w;
  }

  // ---- cost rows, transpose to LDS -----------------------------------------
  sC0[prob][p] = fmaxf(tt - 2.f * cr0 + pp, 0.f);
  sC1[prob][p] = fmaxf(aa - 2.f * cr1 + pp, 0.f);
  __syncthreads();

  if (threadIdx.x >= 64) return;             // Sinkhorn: wave 0 only

  // ---- Sinkhorn, lane-owns-problem layout ----------------------------------
  const int i = threadIdx.x >> 2;            // problem 0..15
  const int q = threadIdx.x & 3;             // quad slot: p in [8q, 8q+8)
  float ka[8], kb[8], W[8], dc[8];
  float sum0 = 0.f, mA = -1e30f, mB = -1e30f;
  #pragma unroll
  for (int r = 0; r < 8; ++r) {
    float c0 = sC0[i][q * 8 + r];
    float c1 = sC1[i][q * 8 + r];
    ka[r] = -c0 * C_SCALE;
    kb[r] = -c1 * C_SCALE;
    dc[r] = c1 - c0;
    sum0 += c0;
    mA = fmaxf(mA, ka[r]);
    mB = fmaxf(mB, kb[r]);
  }
  mA = qmax4(mA);
  mB = qmax4(mB);
  float sa = 0.f, sb = 0.f;
  #pragma unroll
  for (int r = 0; r < 8; ++r) {
    sa += EXP2F(ka[r] - mA);
    sb += EXP2F(kb[r] - mB);
    W[r] = EXP2F(ka[r] - kb[r]);             // 2^(d_p)
  }
  sa = qsum4(sa);
  sb = qsum4(sb);
  // iteration 1 (reference: lv=0): delta1 = lse(kb) - lse(ka)
  float delta = (mB + LOG2F(sb)) - (mA + LOG2F(sa));

  // iterations 2..50
  for (int it = 0; it < 49; ++it) {
    float s = EXP2F(delta);
    float t = 0.f;
    #pragma unroll
    for (int r = 0; r < 8; ++r)
      t += RCPF(__builtin_fmaf(W[r], s, 1.0f));   // sigma_p
    float T = qsum4(t);                      // in (0,32)
    delta += LOG2F(T) - LOG2F(32.0f - T);
  }

  // ---- final transport & outputs -------------------------------------------
  float s = EXP2F(delta);
  float acc = sum0;
  #pragma unroll
  for (int r = 0; r < 8; ++r)
    acc += RCPF(__builtin_fmaf(W[r], s, 1.0f)) * dc[r];
  acc = qsum4(acc);
  if (q == 0) {
    int bb = b0 + i;
    float ot  = acc * 0.03125f;
    float val = RCPF(1.0f + EXP2F(LOG2E * 6.0f * (ot - 0.25f)));
    outVal[bb * EDIM + e] = val;
    outOt [bb * EDIM + e] = ot;
  }
}

extern "C" void kernel_launch(void* const* d_in, const int* in_sizes, int n_in,
                              void* d_out, int out_size, void* d_ws, size_t ws_size,
                              hipStream_t stream) {
  const float* tokens = (const float*)d_in[0];   // (8192, 8, 512) fp32
  const float* protos = (const float*)d_in[1];   // (8, 32, 512) fp32
  const int*   fidx   = (const int*)d_in[2];     // scalar
  float* out = (float*)d_out;                    // 65536 validity + 65536 ot
  float* pn  = (float*)d_ws;                     // 256 floats: ||proto||^2

  proto_norms_kernel<<<1, EDIM * PDIM, 0, stream>>>(protos, pn);
  dim3 grid((BDIM / BPB) * EDIM);                // 4096 blocks
  ot_noise_gate_kernel<<<grid, NTHR, 0, stream>>>(tokens, protos, pn, fidx, out);
}

// Round 3
// 217.664 us; speedup vs baseline: 2.0539x; 2.0410x over previous
//
#include <hip/hip_runtime.h>
#include <hip/hip_bf16.h>

// OTNoiseGate: B=8192, E=8, D=512, P=32, eps=0.05, 50 Sinkhorn iters.
// R3: cost phase as bf16 MFMA GEMM (m92/m97-verified fragment layouts),
// fp32 row norms computed during staging, ns=2 Sinkhorn scalar recurrence
// fused in-block (2 lanes/problem, 16 p each, shfl_xor(1) reductions).

#define EXP2F(x) __builtin_amdgcn_exp2f(x)
#define LOG2F(x) __builtin_amdgcn_logf(x)   // v_log_f32 = log2
#define RCPF(x)  __builtin_amdgcn_rcpf(x)

typedef __bf16 bf16x8 __attribute__((ext_vector_type(8)));
typedef float  f32x4  __attribute__((ext_vector_type(4)));

#define BDIM 8192
#define EDIM 8
#define DDIM 512
#define PDIM 32
#define BPB  128            // b's (problems) per block
#define MROWS 256           // 128 token rows + 128 anchor rows
#define NTHR 256
#define ASTRIDE 72          // bf16 per A-tile row (64 + 8 pad) -> balanced banks
#define BSTRIDE 536         // bf16 per proto row (512 + 24 pad) -> balanced banks
#define CSTRIDE 36          // floats per cost row (32 + 4 pad), 16B-aligned rows
#define C_SCALE 28.853900817779268f   // log2(e)/eps
#define LOG2E   1.4426950408889634f

__device__ __forceinline__ void store_bf16x4(__bf16* dst, float4 v) {
  ushort4 t;
  t.x = __builtin_bit_cast(unsigned short, (__bf16)v.x);
  t.y = __builtin_bit_cast(unsigned short, (__bf16)v.y);
  t.z = __builtin_bit_cast(unsigned short, (__bf16)v.z);
  t.w = __builtin_bit_cast(unsigned short, (__bf16)v.w);
  *(ushort4*)dst = t;                     // one ds_write_b64
}

// ---- pre-kernel: pn[e*32+p] = ||proto_e_p||^2 (8 blocks, one per e) --------
__global__ void proto_norms_kernel(const float* __restrict__ protos,
                                   float* __restrict__ pn) {
  int e = blockIdx.x;
  int p = threadIdx.x >> 3;               // 32 rows, 8 threads per row
  int j = threadIdx.x & 7;
  const float4* row = (const float4*)(protos + ((size_t)e * PDIM + p) * DDIM);
  float s = 0.f;
  #pragma unroll
  for (int k = 0; k < 16; ++k) {
    float4 v = row[j + 8 * k];
    s += v.x * v.x + v.y * v.y + v.z * v.z + v.w * v.w;
  }
  s += __shfl_xor(s, 1);
  s += __shfl_xor(s, 2);
  s += __shfl_xor(s, 4);
  if (j == 0) pn[e * PDIM + p] = s;
}

__global__ __launch_bounds__(NTHR, 2)
void ot_noise_gate_kernel(const float* __restrict__ tokens,
                          const float* __restrict__ protos,
                          const float* __restrict__ pn,
                          const int*   __restrict__ fullIndexPtr,
                          float*       __restrict__ out) {
  const int fi    = fullIndexPtr[0];
  const int e     = blockIdx.x & (EDIM - 1);       // chunk-major: same-chunk
  const int chunk = blockIdx.x >> 3;               // blocks adjacent -> anchor
  const int b0    = chunk * BPB;                   // lines shared via L2/L3
  float* outVal = out;                             // validity (B,E,1)
  float* outOt  = out + BDIM * EDIM;               // ot_cost  (B,E)

  if (e == fi) {
    int t = threadIdx.x;
    if (t < BPB) {
      int b = b0 + t;
      outVal[b * EDIM + e] = 1.0f;
      outOt [b * EDIM + e] = 0.0f;
    }
    return;
  }

  // A-tile (bf16, one K-chunk) and cost tile (fp32) overlay: both 36864 B.
  __shared__ __align__(16) unsigned char sACraw[MROWS * ASTRIDE * 2];
  __shared__ __align__(16) __bf16 sB[PDIM * BSTRIDE];   // full-K protos, 34.3KB
  __shared__ float sNorm[MROWS];
  __bf16* sA = (__bf16*)sACraw;
  float*  sC = (float*)sACraw;

  const int t    = threadIdx.x;
  const int l    = t & 63;
  const int w    = t >> 6;            // wave 0..3
  const int fr   = l & 15;            // fragment row/col lane index
  const int oct  = l >> 4;            // k-octet selector

  // ---- stage protos[e] -> bf16 LDS (once, full K) --------------------------
  {
    const float4* pG4 = (const float4*)(protos + (size_t)e * PDIM * DDIM);
    #pragma unroll
    for (int it = 0; it < 16; ++it) {
      int idx = it * NTHR + t;        // 0..4095 ; p = idx>>7, j = idx&127
      float4 v = pG4[idx];
      store_bf16x4(&sB[(idx >> 7) * BSTRIDE + (idx & 127) * 4], v);
    }
  }

  // ---- K-chunk loop: stage A (256 rows x 64 floats, bf16) + MFMA -----------
  const int g = t >> 4;               // row subgroup 0..15
  const int j = t & 15;               // float4 index within 64-float chunk
  const float4* tokB = (const float4*)(tokens + ((size_t)(b0 + g) * EDIM + e)  * DDIM);
  const float4* ancB = (const float4*)(tokens + ((size_t)(b0 + g) * EDIM + fi) * DDIM);
  const int rowStrF4 = 16 * EDIM * DDIM / 4;   // 16 b's in float4 units

  float ss[16];
  #pragma unroll
  for (int r = 0; r < 16; ++r) ss[r] = 0.f;

  f32x4 acc[4][2];
  #pragma unroll
  for (int mt = 0; mt < 4; ++mt)
    #pragma unroll
    for (int nt = 0; nt < 2; ++nt)
      acc[mt][nt] = (f32x4){0.f, 0.f, 0.f, 0.f};

  for (int kc = 0; kc < 8; ++kc) {
    #pragma unroll
    for (int it = 0; it < 8; ++it) {            // token rows: row = it*16+g
      float4 v = tokB[it * rowStrF4 + kc * 16 + j];
      ss[it] += v.x * v.x + v.y * v.y + v.z * v.z + v.w * v.w;
      store_bf16x4(&sA[(it * 16 + g) * ASTRIDE + j * 4], v);
    }
    #pragma unroll
    for (int it = 0; it < 8; ++it) {            // anchor rows: row = 128+it*16+g
      float4 v = ancB[it * rowStrF4 + kc * 16 + j];
      ss[8 + it] += v.x * v.x + v.y * v.y + v.z * v.z + v.w * v.w;
      store_bf16x4(&sA[((8 + it) * 16 + g) * ASTRIDE + j * 4], v);
    }
    __syncthreads();

    #pragma unroll
    for (int ks = 0; ks < 2; ++ks) {
      bf16x8 b0f = *(const bf16x8*)&sB[(fr)      * BSTRIDE + kc * 64 + ks * 32 + oct * 8];
      bf16x8 b1f = *(const bf16x8*)&sB[(16 + fr) * BSTRIDE + kc * 64 + ks * 32 + oct * 8];
      #pragma unroll
      for (int mt = 0; mt < 4; ++mt) {
        bf16x8 af = *(const bf16x8*)&sA[(w * 64 + mt * 16 + fr) * ASTRIDE + ks * 32 + oct * 8];
        acc[mt][0] = __builtin_amdgcn_mfma_f32_16x16x32_bf16(af, b0f, acc[mt][0], 0, 0, 0);
        acc[mt][1] = __builtin_amdgcn_mfma_f32_16x16x32_bf16(af, b1f, acc[mt][1], 0, 0, 0);
      }
    }
    __syncthreads();
  }

  // ---- fp32 row norms: reduce ss across the 16 threads sharing each row ----
  #pragma unroll
  for (int it = 0; it < 16; ++it) {
    float v = ss[it];
    v += __shfl_xor(v, 1);
    v += __shfl_xor(v, 2);
    v += __shfl_xor(v, 4);
    v += __shfl_xor(v, 8);
    if (j == 0) sNorm[it * 16 + g] = v;
  }
  __syncthreads();

  // ---- epilogue: cost = max(||x||^2 - 2*cross + ||p||^2, 0) -> sC ----------
  {
    float pp0 = pn[e * PDIM + fr];
    float pp1 = pn[e * PDIM + 16 + fr];
    #pragma unroll
    for (int mt = 0; mt < 4; ++mt)
      #pragma unroll
      for (int reg = 0; reg < 4; ++reg) {
        int row = w * 64 + mt * 16 + oct * 4 + reg;   // C/D: row=(l>>4)*4+reg
        float nrm = sNorm[row];
        sC[row * CSTRIDE + fr]      = fmaxf(nrm - 2.f * acc[mt][0][reg] + pp0, 0.f);
        sC[row * CSTRIDE + 16 + fr] = fmaxf(nrm - 2.f * acc[mt][1][reg] + pp1, 0.f);
      }
  }
  __syncthreads();

  // ---- Sinkhorn: 2 lanes per problem, 16 p each ----------------------------
  const int i = t >> 1;               // problem 0..127
  const int h = t & 1;                // half: p in [16h, 16h+16)
  const float4* r0 = (const float4*)&sC[i * CSTRIDE];          // c0 (token)
  const float4* r1 = (const float4*)&sC[(128 + i) * CSTRIDE];  // c1 (anchor)
  float c0[16], c1[16];
  #pragma unroll
  for (int r = 0; r < 4; ++r) {
    float4 a = r0[h * 4 + r];
    float4 b = r1[h * 4 + r];
    c0[4*r] = a.x; c0[4*r+1] = a.y; c0[4*r+2] = a.z; c0[4*r+3] = a.w;
    c1[4*r] = b.x; c1[4*r+1] = b.y; c1[4*r+2] = b.z; c1[4*r+3] = b.w;
  }

  float W[16], dc[16];
  float sum0 = 0.f, mA = -1e30f, mB = -1e30f;
  #pragma unroll
  for (int r = 0; r < 16; ++r) {
    float ka = -c0[r] * C_SCALE, kb = -c1[r] * C_SCALE;
    dc[r] = c1[r] - c0[r];
    sum0 += c0[r];
    mA = fmaxf(mA, ka);
    mB = fmaxf(mB, kb);
  }
  mA = fmaxf(mA, __shfl_xor(mA, 1));
  mB = fmaxf(mB, __shfl_xor(mB, 1));
  float sa = 0.f, sb = 0.f;
  #pragma unroll
  for (int r = 0; r < 16; ++r) {
    float ka = -c0[r] * C_SCALE, kb = -c1[r] * C_SCALE;
    sa += EXP2F(ka - mA);
    sb += EXP2F(kb - mB);
    W[r] = EXP2F(C_SCALE * dc[r]);    // 2^(ka-kb)
  }
  sa += __shfl_xor(sa, 1);
  sb += __shfl_xor(sb, 1);
  sum0 += __shfl_xor(sum0, 1);
  // iteration 1 (reference: lv=0): delta1 = lse2(kb) - lse2(ka)
  float delta = (mB + LOG2F(sb)) - (mA + LOG2F(sa));

  // iterations 2..50
  for (int it = 0; it < 49; ++it) {
    float s = EXP2F(delta);
    float T = 0.f;
    #pragma unroll
    for (int r = 0; r < 16; ++r)
      T += RCPF(__builtin_fmaf(W[r], s, 1.0f));   // sigma_p
    T += __shfl_xor(T, 1);            // in (0,32)
    delta += LOG2F(T) - LOG2F(32.0f - T);
  }

  // ---- final transport & outputs -------------------------------------------
  float s = EXP2F(delta), sv = 0.f;
  #pragma unroll
  for (int r = 0; r < 16; ++r)
    sv += RCPF(__builtin_fmaf(W[r], s, 1.0f)) * dc[r];
  sv += __shfl_xor(sv, 1);
  if (h == 0) {
    int b = b0 + i;
    float ot  = (sum0 + sv) * 0.03125f;
    float val = RCPF(1.0f + EXP2F(LOG2E * 6.0f * (ot - 0.25f)));
    outVal[b * EDIM + e] = val;
    outOt [b * EDIM + e] = ot;
  }
}

extern "C" void kernel_launch(void* const* d_in, const int* in_sizes, int n_in,
                              void* d_out, int out_size, void* d_ws, size_t ws_size,
                              hipStream_t stream) {
  const float* tokens = (const float*)d_in[0];   // (8192, 8, 512) fp32
  const float* protos = (const float*)d_in[1];   // (8, 32, 512) fp32
  const int*   fidx   = (const int*)d_in[2];     // scalar
  float* out = (float*)d_out;                    // 65536 validity + 65536 ot
  float* pn  = (float*)d_ws;                     // 256 floats: ||proto||^2

  proto_norms_kernel<<<EDIM, NTHR, 0, stream>>>(protos, pn);
  dim3 grid((BDIM / BPB) * EDIM);                // 512 blocks, chunk-major
  ot_noise_gate_kernel<<<grid, NTHR, 0, stream>>>(tokens, protos, pn, fidx, out);
}